// Round 18
// baseline (596.521 us; speedup 1.0000x reference)
//
#include <hip/hip_runtime.h>
#include <hip/hip_cooperative_groups.h>

namespace cg = cooperative_groups;

#define CONC_N 2000
#define ITEM_N 20000
#define STU_N  50000
#define NE_CC  40000
#define NE_IC  80000
#define NE_SI  1000000
#define TBUCK  382   // 63+63+79+79+98

#define NB_PART 600
#define NB_GEMM 1472
#define NB_RDOT 1024
#define NB_B    (NB_PART + NB_GEMM + NB_RDOT)
#define NB_I12  1250
#define NB_S1   3125
#define NB_CC   125
#define NB_D    (NB_I12 + NB_S1 + 2 * NB_CC)
#define NB_E    500

typedef unsigned int uint;
typedef unsigned short ushort;
typedef signed char s8;
typedef __attribute__((ext_vector_type(8))) short bf16x8;
typedef __attribute__((ext_vector_type(4))) float f32x4;

__device__ __forceinline__ ushort f2bf(float f) {
  uint u = __float_as_uint(f);
  uint r = (u + 0x7FFFu + ((u >> 16) & 1u)) >> 16;
  return (ushort)r;
}

__device__ __forceinline__ bf16x8 packfrag(float4 lo, float4 hi) {
  union { bf16x8 s; uint u[4]; } p;
  p.u[0] = (uint)f2bf(lo.x) | ((uint)f2bf(lo.y) << 16);
  p.u[1] = (uint)f2bf(lo.z) | ((uint)f2bf(lo.w) << 16);
  p.u[2] = (uint)f2bf(hi.x) | ((uint)f2bf(hi.y) << 16);
  p.u[3] = (uint)f2bf(hi.z) | ((uint)f2bf(hi.w) << 16);
  return p.s;
}

// ---------------- structs ----------------

struct CsrG {
  const int* dst; const int* src;
  unsigned* keys; int* srcs; int* offs;
  int E, n, shift, nbuck, tb, sb;
};
struct CsrGs { CsrG g[5]; };

struct ProjDesc { const float* W; const float* a; float* out; };

struct GemmDesc { const float* X; s8* Y8; float2* SS; int n, b0;
                  const float* dv[6]; float* dq[6]; int ds[6]; };
struct BigC { GemmDesc g[5]; };

struct GatsArgs {
  const int *offs4, *srcs4; const float2* ssc_is; const float* sr_is;
  const s8* x_is; const float* stu_raw_x; float* out_stu;
  const int *offs3, *srcs3; const float2* ssc_si; const float* sr_si; const s8* x_si;
  const int *offs2, *srcs2; const float2* ssc_ci; const float* sr_ci; const s8* x_ci;
  const float* item_x; float* out_item;
  const int *offs0, *srcs0; const float2* ssc_cc; const float* sr_cc; const s8* x_cc;
  const float* al_cce; float *c1, *sl_cce;
  const int *offs1, *srcs1; const float2* ssc_ic; const float* sr_ic; const s8* x_ic;
  const float* al_ice; float *c2, *sl_ice;
};

struct MegaArgs {
  ProjDesc p[10];
  CsrGs G;
  int* pcnt;
  const float* wsrc[5];
  ushort* wdst[5];
  int* cur; int* bases;
  BigC C;
  const float* rx; const float* rv; float* ro;
  GatsArgs GA;
  const float* sr_cce; const float* sr_ice;
  const float* conc_x; float* out_conc;
};

// ---------------- phase bodies ----------------

__device__ void proj_body(const ProjDesc& d) {
  int tid = threadIdx.x;
  if (tid < 128) {
    float acc = 0.f;
    #pragma unroll 4
    for (int j = 0; j < 128; ++j) acc += d.W[j * 128 + tid] * d.a[j];
    d.out[tid] = acc;
  }
}

__device__ void wconv_body(const float* __restrict__ Ws, ushort* __restrict__ Wd) {
  int tid = threadIdx.x;
  for (int rec = tid; rec < 2048; rec += 256) {
    int lane = rec & 63;
    int kk = (rec >> 6) & 3;
    int nt = rec >> 8;
    int x = lane & 15, g = lane >> 4;
    const float* src = &Ws[(nt * 16 + x) * 128 + kk * 32 + 4 * g];
    float4 lo = *(const float4*)src;
    float4 hi = *(const float4*)(src + 16);
    bf16x8 pk = packfrag(lo, hi);
    *(bf16x8*)&Wd[rec * 8] = pk;
  }
}

__device__ void hist_body(const CsrGs& G, int* __restrict__ pcnt, int bsel,
                          unsigned char* smem) {
  int* lcnt = (int*)smem;
  int tid = threadIdx.x;
  int gi = bsel >> 5, blk = bsel & 31;
  CsrG g = G.g[gi];
  if (tid < 128) lcnt[tid] = 0;
  __syncthreads();
  int chunk = (g.E + 31) >> 5;
  int e0 = blk * chunk, e1 = min(g.E, e0 + chunk);
  for (int e = e0 + tid; e < e1; e += 256)
    atomicAdd(&lcnt[g.dst[e] >> g.shift], 1);
  __syncthreads();
  if (tid < 128) pcnt[bsel * 128 + tid] = lcnt[tid];
  __syncthreads();
}

__device__ void scan_body(const CsrGs& G, const int* __restrict__ pcnt,
                          int* __restrict__ cur, int* __restrict__ bases,
                          unsigned char* smem) {
  int* lc = (int*)smem;              // 382 ints
  int* lb = (int*)(smem + 2048);     // 387 ints
  int tid = threadIdx.x;
  for (int i = tid; i < TBUCK; i += 256) {
    int gi = 0;
    #pragma unroll
    for (int k = 1; k < 5; ++k) if (i >= G.g[k].tb) gi = k;
    int b = i - G.g[gi].tb;
    int s = 0;
    for (int blk = 0; blk < 32; ++blk) s += pcnt[((gi << 5) + blk) * 128 + b];
    lc[i] = s;
  }
  __syncthreads();
  int lane = tid & 63, wv = tid >> 6;
  if (wv == 0) {
    for (int gi = 0; gi < 5; ++gi) {
      CsrG g = G.g[gi];
      int carry = 0;
      for (int base = 0; base < g.nbuck; base += 64) {
        int idx = base + lane;
        int v = (idx < g.nbuck) ? lc[g.tb + idx] : 0;
        int incl = v;
        #pragma unroll
        for (int o = 1; o < 64; o <<= 1) {
          int y = __shfl_up(incl, o);
          if (lane >= o) incl += y;
        }
        if (idx < g.nbuck) lb[g.sb + idx] = carry + incl - v;
        carry += __shfl(incl, 63);
      }
      if (lane == 0) lb[g.sb + g.nbuck] = carry;
    }
  }
  __syncthreads();
  for (int i = tid; i < TBUCK + 5; i += 256) bases[i] = lb[i];
  for (int i = tid; i < TBUCK; i += 256) {
    int gi = 0;
    for (int k = 1; k < 5; ++k) if (i >= G.g[k].tb) gi = k;
    cur[i] = lb[i + gi];
  }
  if (tid < 5) G.g[tid].offs[G.g[tid].n] = G.g[tid].E;
  __syncthreads();
}

__device__ void partition_body(const CsrGs& G, int* __restrict__ cur, int gi, int bx,
                               int nbx, unsigned char* smem) {
  CsrG g = G.g[gi];
  unsigned* ck = (unsigned*)smem;                 // 16384 B
  unsigned char* cb = smem + 16384;               // 4096 B
  int* lcnt = (int*)(smem + 20480);               // 512 B
  int* lcur = (int*)(smem + 20992);               // 512 B
  int tid = threadIdx.x;
  unsigned dmask = (1u << g.shift) - 1;
  for (int c0 = bx * 4096; c0 < g.E; c0 += nbx * 4096) {
    if (tid < 128) lcnt[tid] = 0;
    __syncthreads();
    #pragma unroll
    for (int i = 0; i < 16; ++i) {
      int e = c0 + i * 256 + tid;
      if (e < g.E) {
        int d = g.dst[e], s = g.src[e];
        int b = d >> g.shift;
        ck[i * 256 + tid] = ((unsigned)(d & dmask) << 16) | (unsigned)s;
        cb[i * 256 + tid] = (unsigned char)b;
        atomicAdd(&lcnt[b], 1);
      } else cb[i * 256 + tid] = 255;
    }
    __syncthreads();
    if (tid < g.nbuck && lcnt[tid] > 0) lcur[tid] = atomicAdd(&cur[g.tb + tid], lcnt[tid]);
    __syncthreads();
    #pragma unroll
    for (int i = 0; i < 16; ++i) {
      int b = cb[i * 256 + tid];
      if (b != 255) {
        int pos = atomicAdd(&lcur[b], 1);
        g.keys[pos] = ck[i * 256 + tid];
      }
    }
    __syncthreads();
  }
}

__device__ void rdot_body(const float* __restrict__ x, const float* __restrict__ v,
                          float* __restrict__ o, int n, int blk, int nblk) {
  int lane = threadIdx.x & 63;
  int wid = (blk * 256 + threadIdx.x) >> 6;
  int nw = nblk * 4;
  float va = v[lane], vb = v[64 + lane];
  for (int r = wid; r < n; r += nw) {
    float a = x[r * 128 + lane] * va + x[r * 128 + 64 + lane] * vb;
    #pragma unroll
    for (int of = 32; of; of >>= 1) a += __shfl_xor(a, of);
    if (lane == 0) o[r] = a;
  }
}

template <int NV>
__device__ void gemm_bodyT(const GemmDesc& gd, const ushort* __restrict__ Wf, int blk) {
  int tid = threadIdx.x;
  int lane = tid & 63, wv = tid >> 6;
  int x = lane & 15, g = lane >> 4;
  int row = blk * 64 + wv * 16 + x;
  const float* xr = &gd.X[(size_t)(row < gd.n ? row : 0) * 128];
  bf16x8 afrag[4];
  float dacc[NV == 0 ? 1 : NV];
  #pragma unroll
  for (int v = 0; v < NV; ++v) dacc[v] = 0.f;
  #pragma unroll
  for (int kk = 0; kk < 4; ++kk) {
    float4 lo = *(const float4*)&xr[kk * 32 + 4 * g];
    float4 hi = *(const float4*)&xr[kk * 32 + 16 + 4 * g];
    afrag[kk] = packfrag(lo, hi);
    #pragma unroll
    for (int v = 0; v < NV; ++v) {
      const float* vp = gd.dv[v];
      float4 vlo = *(const float4*)&vp[kk * 32 + 4 * g];
      float4 vhi = *(const float4*)&vp[kk * 32 + 16 + 4 * g];
      dacc[v] += lo.x * vlo.x + lo.y * vlo.y + lo.z * vlo.z + lo.w * vlo.w
               + hi.x * vhi.x + hi.y * vhi.y + hi.z * vhi.z + hi.w * vhi.w;
    }
  }
  #pragma unroll
  for (int v = 0; v < NV; ++v) {
    float dsum = dacc[v];
    dsum += __shfl_xor(dsum, 16);
    dsum += __shfl_xor(dsum, 32);
    if (lane < 16 && row < gd.n) gd.dq[v][(size_t)row * gd.ds[v]] = dsum;
  }
  f32x4 acc[8];
  #pragma unroll
  for (int t = 0; t < 8; ++t) acc[t] = (f32x4){0.f, 0.f, 0.f, 0.f};
  #pragma unroll
  for (int nt = 0; nt < 8; ++nt) {
    #pragma unroll
    for (int kk = 0; kk < 4; ++kk) {
      union { uint4 u; bf16x8 s; } bu;
      bu.u = *(const uint4*)&Wf[(size_t)((nt * 4 + kk) * 64 + lane) * 8];
      acc[nt] = __builtin_amdgcn_mfma_f32_16x16x32_bf16(afrag[kk], bu.s, acc[nt], 0, 0, 0);
    }
  }
  int orow = blk * 64 + wv * 16 + 4 * g;
  #pragma unroll
  for (int r = 0; r < 4; ++r) {
    float m8 = 0.f;
    #pragma unroll
    for (int nt = 0; nt < 8; ++nt) m8 = fmaxf(m8, fabsf(acc[nt][r]));
    #pragma unroll
    for (int msk = 1; msk < 16; msk <<= 1) m8 = fmaxf(m8, __shfl_xor(m8, msk));
    int gr = orow + r;
    if (gr < gd.n) {
      float invs = (m8 > 0.f) ? 127.f / m8 : 0.f;
      if (x == 0) gd.SS[gr].y = m8 * (1.f / 127.f);
      #pragma unroll
      for (int nt = 0; nt < 8; ++nt) {
        int q = (int)rintf(acc[nt][r] * invs);
        gd.Y8[(size_t)gr * 128 + nt * 16 + x] = (s8)q;
      }
    }
  }
}

__device__ void build_lite(const CsrGs& G, const int* __restrict__ bases, int bid,
                           unsigned char* smem) {
  int* lh = (int*)smem;
  int* lex = (int*)(smem + 2048);
  int* lcu = (int*)(smem + 4096);
  int* wsum = (int*)(smem + 6144);
  int gi = 0;
  for (int k = 1; k < 5; ++k) if (bid >= G.g[k].tb) gi = k;
  CsrG g = G.g[gi];
  int b = bid - g.tb;
  int base = bases[g.sb + b];
  int cnt = bases[g.sb + b + 1] - base;

  int tid = threadIdx.x;
  lh[tid] = 0; lh[tid + 256] = 0;
  __syncthreads();
  for (int j = tid; j < cnt; j += 256)
    atomicAdd(&lh[g.keys[base + j] >> 16], 1);
  __syncthreads();
  int a0 = lh[2 * tid], a1 = lh[2 * tid + 1];
  int pair = a0 + a1;
  int lane = tid & 63, wv = tid >> 6;
  int incl = pair;
  #pragma unroll
  for (int o = 1; o < 64; o <<= 1) {
    int y = __shfl_up(incl, o);
    if (lane >= o) incl += y;
  }
  if (lane == 63) wsum[wv] = incl;
  __syncthreads();
  if (tid == 0) {
    int s = 0;
    #pragma unroll
    for (int w = 0; w < 4; ++w) { int t = wsum[w]; wsum[w] = s; s += t; }
  }
  __syncthreads();
  int ep = wsum[wv] + incl - pair;
  lex[2 * tid] = ep;       lex[2 * tid + 1] = ep + a0;
  lcu[2 * tid] = ep;       lcu[2 * tid + 1] = ep + a0;
  __syncthreads();
  int dst0 = b << g.shift;
  int ndst = min(1 << g.shift, g.n - dst0);
  for (int dl = tid; dl < ndst; dl += 256) g.offs[dst0 + dl] = base + lex[dl];
  for (int j = tid; j < cnt; j += 256) {
    unsigned k = g.keys[base + j];
    int dl = k >> 16;
    int pos = atomicAdd(&lcu[dl], 1);
    g.srcs[base + pos] = (int)(k & 0xFFFFu);
  }
  __syncthreads();
}

// ---------------- GAT cores ----------------

__device__ __forceinline__ void fma8q(float acc[8], float wj, uint2 u) {
  int lo = (int)u.x, hi = (int)u.y;
  acc[0] += wj * (float)((lo << 24) >> 24);
  acc[1] += wj * (float)((lo << 16) >> 24);
  acc[2] += wj * (float)((lo << 8) >> 24);
  acc[3] += wj * (float)(lo >> 24);
  acc[4] += wj * (float)((hi << 24) >> 24);
  acc[5] += wj * (float)((hi << 16) >> 24);
  acc[6] += wj * (float)((hi << 8) >> 24);
  acc[7] += wj * (float)(hi >> 24);
}

__device__ void gat_core16(const int* __restrict__ offs, const int* __restrict__ srcs,
                           const float2* __restrict__ ssc, const float* __restrict__ sr,
                           const s8* __restrict__ x8,
                           int t4, int n_tgt, int lane, float acc[8]) {
  int q = lane >> 4, il = lane & 15;
  int t = t4 + q;
  bool tv = t < n_tgt;
  int sbeg = tv ? offs[t] : 0;
  int send = tv ? offs[t + 1] : 0;
  float srt = tv ? sr[t] : 0.f;

  float se = 0.f;
  #pragma unroll
  for (int r = 0; r < 8; ++r) acc[r] = 0.f;
  int qb = q << 4;

  for (int i0 = sbeg; i0 < send; i0 += 16) {
    int cnt = min(16, send - i0);
    int s = 0; float w = 0.f, ws = 0.f;
    if (il < cnt) {
      s = srcs[i0 + il];
      float2 ss = ssc[s];
      float ee = ss.x + srt;
      ee = ee > 0.f ? ee : 0.2f * ee;
      w = __expf(fminf(ee, 80.f));
      ws = w * ss.y;
    }
    se += w;
    int j = 0;
    for (; j + 4 <= cnt; j += 4) {
      int sj0 = __shfl(s, qb + j);
      int sj1 = __shfl(s, qb + j + 1);
      int sj2 = __shfl(s, qb + j + 2);
      int sj3 = __shfl(s, qb + j + 3);
      float wj0 = __shfl(ws, qb + j);
      float wj1 = __shfl(ws, qb + j + 1);
      float wj2 = __shfl(ws, qb + j + 2);
      float wj3 = __shfl(ws, qb + j + 3);
      uint2 u0 = *(const uint2*)&x8[(size_t)sj0 * 128 + il * 8];
      uint2 u1 = *(const uint2*)&x8[(size_t)sj1 * 128 + il * 8];
      uint2 u2 = *(const uint2*)&x8[(size_t)sj2 * 128 + il * 8];
      uint2 u3 = *(const uint2*)&x8[(size_t)sj3 * 128 + il * 8];
      fma8q(acc, wj0, u0);
      fma8q(acc, wj1, u1);
      fma8q(acc, wj2, u2);
      fma8q(acc, wj3, u3);
    }
    for (; j < cnt; ++j) {
      int sj = __shfl(s, qb + j);
      float wj = __shfl(ws, qb + j);
      uint2 u = *(const uint2*)&x8[(size_t)sj * 128 + il * 8];
      fma8q(acc, wj, u);
    }
  }
  #pragma unroll
  for (int o = 8; o; o >>= 1) se += __shfl_xor(se, o);
  float inv = 1.f / (se + 1e-16f);
  #pragma unroll
  for (int r = 0; r < 8; ++r) acc[r] *= inv;
}

__device__ __forceinline__ void gat_store16(const float acc[8], const float* base0,
                                            float* out, int t4, int n_tgt, int lane) {
  int q = lane >> 4, il = lane & 15;
  int t = t4 + q;
  if (t >= n_tgt) return;
  int d = t * 128 + il * 8;
  float4 a0 = make_float4(acc[0], acc[1], acc[2], acc[3]);
  float4 a1 = make_float4(acc[4], acc[5], acc[6], acc[7]);
  if (base0) {
    const float4 b0 = *(const float4*)&base0[d];
    const float4 b1 = *(const float4*)&base0[d + 4];
    a0.x += b0.x; a0.y += b0.y; a0.z += b0.z; a0.w += b0.w;
    a1.x += b1.x; a1.y += b1.y; a1.z += b1.z; a1.w += b1.w;
  }
  *(float4*)&out[d] = a0;
  *(float4*)&out[d + 4] = a1;
}

__device__ void c1c2_body16(const int* offs, const int* srcs, const float2* ssc,
                            const float* sr, const s8* x8,
                            const float* al, float* o, float* slo,
                            int t4, int n_tgt, int lane) {
  float acc[8];
  gat_core16(offs, srcs, ssc, sr, x8, t4, n_tgt, lane, acc);
  int q = lane >> 4, il = lane & 15;
  int t = t4 + q;
  float4 v0 = *(const float4*)&al[il * 8];
  float4 v1 = *(const float4*)&al[il * 8 + 4];
  float p = acc[0] * v0.x + acc[1] * v0.y + acc[2] * v0.z + acc[3] * v0.w +
            acc[4] * v1.x + acc[5] * v1.y + acc[6] * v1.z + acc[7] * v1.w;
  #pragma unroll
  for (int o2 = 8; o2; o2 >>= 1) p += __shfl_xor(p, o2);
  if (t < n_tgt) {
    if (il == 0) slo[t] = p;
    int d = t * 128 + il * 8;
    *(float4*)&o[d] = make_float4(acc[0], acc[1], acc[2], acc[3]);
    *(float4*)&o[d + 4] = make_float4(acc[4], acc[5], acc[6], acc[7]);
  }
}

__device__ void gat_dual_core(const int* __restrict__ offs, const int* __restrict__ srcs,
                              const float* __restrict__ sl1, const float* __restrict__ sr1,
                              const float* __restrict__ xl1,
                              const float* __restrict__ sl2, const float* __restrict__ sr2,
                              const float* __restrict__ xl2,
                              const float* __restrict__ base,
                              float* __restrict__ out, int t, int lane) {
  int sbeg = offs[t], send = offs[t + 1];
  float srt1 = sr1[t], srt2 = sr2[t];
  float m1 = -1e30f, m2 = -1e30f;
  for (int i = sbeg + lane; i < send; i += 64) {
    int s = srcs[i];
    float e1 = sl1[s] + srt1; e1 = e1 > 0.f ? e1 : 0.2f * e1;
    float e2 = sl2[s] + srt2; e2 = e2 > 0.f ? e2 : 0.2f * e2;
    m1 = fmaxf(m1, e1); m2 = fmaxf(m2, e2);
  }
  #pragma unroll
  for (int o = 32; o; o >>= 1) {
    m1 = fmaxf(m1, __shfl_xor(m1, o));
    m2 = fmaxf(m2, __shfl_xor(m2, o));
  }
  float se1 = 0.f, se2 = 0.f;
  for (int i = sbeg + lane; i < send; i += 64) {
    int s = srcs[i];
    float e1 = sl1[s] + srt1; e1 = e1 > 0.f ? e1 : 0.2f * e1;
    float e2 = sl2[s] + srt2; e2 = e2 > 0.f ? e2 : 0.2f * e2;
    se1 += __expf(e1 - m1); se2 += __expf(e2 - m2);
  }
  #pragma unroll
  for (int o = 32; o; o >>= 1) {
    se1 += __shfl_xor(se1, o);
    se2 += __shfl_xor(se2, o);
  }
  float inv1 = 1.f / (se1 + 1e-16f), inv2 = 1.f / (se2 + 1e-16f);
  float ax = 0.f, ay = 0.f;
  for (int i0 = sbeg; i0 < send; i0 += 64) {
    int cnt = min(64, send - i0);
    int s = 0; float w1 = 0.f, w2 = 0.f;
    if (lane < cnt) {
      s = srcs[i0 + lane];
      float e1 = sl1[s] + srt1; e1 = e1 > 0.f ? e1 : 0.2f * e1;
      float e2 = sl2[s] + srt2; e2 = e2 > 0.f ? e2 : 0.2f * e2;
      w1 = __expf(e1 - m1) * inv1;
      w2 = __expf(e2 - m2) * inv2;
    }
    for (int j = 0; j < cnt; ++j) {
      int sj = __shfl(s, j);
      float wj1 = __shfl(w1, j);
      float wj2 = __shfl(w2, j);
      const float2 v1 = *(const float2*)&xl1[sj * 128 + lane * 2];
      const float2 v2 = *(const float2*)&xl2[sj * 128 + lane * 2];
      ax += wj1 * v1.x + wj2 * v2.x;
      ay += wj1 * v1.y + wj2 * v2.y;
    }
  }
  const float2 b = *(const float2*)&base[t * 128 + lane * 2];
  float2 o2; o2.x = ax + b.x; o2.y = ay + b.y;
  *(float2*)&out[t * 128 + lane * 2] = o2;
}

// ---------------- phase dispatchers ----------------

__device__ void phaseA(const MegaArgs& A, int vb, unsigned char* smem) {
  if (vb < 10) proj_body(A.p[vb]);
  else if (vb >= 170) wconv_body(A.wsrc[vb - 170], A.wdst[vb - 170]);
  else hist_body(A.G, A.pcnt, vb - 10, smem);
}

__device__ void phaseB(const MegaArgs& A, int vb, unsigned char* smem) {
  if (vb < NB_PART) {
    partition_body(A.G, A.cur, vb / 120, vb % 120, 120, smem);
  } else if (vb < NB_PART + NB_GEMM) {
    int b = vb - NB_PART;
    const BigC& C = A.C;
    if (b < C.g[1].b0)      gemm_bodyT<6>(C.g[0], A.wdst[0], b - C.g[0].b0);
    else if (b < C.g[2].b0) gemm_bodyT<4>(C.g[1], A.wdst[1], b - C.g[1].b0);
    else if (b < C.g[3].b0) gemm_bodyT<0>(C.g[2], A.wdst[2], b - C.g[2].b0);
    else if (b < C.g[4].b0) gemm_bodyT<1>(C.g[3], A.wdst[3], b - C.g[3].b0);
    else                    gemm_bodyT<0>(C.g[4], A.wdst[4], b - C.g[4].b0);
  } else {
    rdot_body(A.rx, A.rv, A.ro, STU_N, vb - NB_PART - NB_GEMM, NB_RDOT);
  }
}

__device__ void phaseD(const MegaArgs& A, int vb) {
  const GatsArgs& GA = A.GA;
  int lane = threadIdx.x & 63;
  int wv = threadIdx.x >> 6;
  if (vb < NB_I12) {
    int t4 = vb * 16 + wv * 4;
    float acc1[8], acc2[8];
    gat_core16(GA.offs2, GA.srcs2, GA.ssc_ci, GA.sr_ci, GA.x_ci, t4, ITEM_N, lane, acc1);
    gat_core16(GA.offs3, GA.srcs3, GA.ssc_si, GA.sr_si, GA.x_si, t4, ITEM_N, lane, acc2);
    #pragma unroll
    for (int r = 0; r < 8; ++r) acc1[r] += acc2[r];
    gat_store16(acc1, GA.item_x, GA.out_item, t4, ITEM_N, lane);
  } else if (vb < NB_I12 + NB_S1) {
    int t4 = (vb - NB_I12) * 16 + wv * 4;
    float acc[8];
    gat_core16(GA.offs4, GA.srcs4, GA.ssc_is, GA.sr_is, GA.x_is, t4, STU_N, lane, acc);
    gat_store16(acc, GA.stu_raw_x, GA.out_stu, t4, STU_N, lane);
  } else {
    int sub = vb - NB_I12 - NB_S1;
    int which = sub >= NB_CC;
    int t4 = (sub - which * NB_CC) * 16 + wv * 4;
    if (!which)
      c1c2_body16(GA.offs0, GA.srcs0, GA.ssc_cc, GA.sr_cc, GA.x_cc, GA.al_cce,
                  GA.c1, GA.sl_cce, t4, CONC_N, lane);
    else
      c1c2_body16(GA.offs1, GA.srcs1, GA.ssc_ic, GA.sr_ic, GA.x_ic, GA.al_ice,
                  GA.c2, GA.sl_ice, t4, CONC_N, lane);
  }
}

__device__ void phaseE(const MegaArgs& A, int vb) {
  int t = (vb * 256 + (int)threadIdx.x) >> 6;
  if (t < CONC_N)
    gat_dual_core(A.GA.offs0, A.GA.srcs0, A.GA.sl_cce, A.sr_cce, A.GA.c1,
                  A.GA.sl_ice, A.sr_ice, A.GA.c2, A.conc_x, A.out_conc,
                  t, threadIdx.x & 63);
}

// ---------------- mega kernel (cooperative) ----------------

__global__ __launch_bounds__(256, 4) void mega_k(MegaArgs A) {
  __shared__ __align__(16) unsigned char smem[21504];
  cg::grid_group grid = cg::this_grid();
  int nb = gridDim.x;
  for (int vb = blockIdx.x; vb < 175; vb += nb) phaseA(A, vb, smem);
  grid.sync();
  if (blockIdx.x == 0) scan_body(A.G, A.pcnt, A.cur, A.bases, smem);
  grid.sync();
  for (int vb = blockIdx.x; vb < NB_B; vb += nb) phaseB(A, vb, smem);
  grid.sync();
  for (int vb = blockIdx.x; vb < TBUCK; vb += nb) build_lite(A.G, A.bases, vb, smem);
  grid.sync();
  for (int vb = blockIdx.x; vb < NB_D; vb += nb) phaseD(A, vb);
  grid.sync();
  for (int vb = blockIdx.x; vb < NB_E; vb += nb) phaseE(A, vb);
}

// ---------------- fallback kernels (same bodies, serial launches) ---------

__global__ __launch_bounds__(256) void f_A(MegaArgs A) {
  __shared__ __align__(16) unsigned char smem[21504];
  phaseA(A, blockIdx.x, smem);
}
__global__ __launch_bounds__(256) void f_scan(MegaArgs A) {
  __shared__ __align__(16) unsigned char smem[8192];
  scan_body(A.G, A.pcnt, A.cur, A.bases, smem);
}
__global__ __launch_bounds__(256, 2) void f_B(MegaArgs A) {
  __shared__ __align__(16) unsigned char smem[21504];
  phaseB(A, blockIdx.x, smem);
}
__global__ __launch_bounds__(256) void f_C(MegaArgs A) {
  __shared__ __align__(16) unsigned char smem[8192];
  build_lite(A.G, A.bases, blockIdx.x, smem);
}
__global__ __launch_bounds__(256) void f_D(MegaArgs A) {
  phaseD(A, blockIdx.x);
}
__global__ __launch_bounds__(256) void f_E(MegaArgs A) {
  phaseE(A, blockIdx.x);
}

// ---------------- launch ----------------

extern "C" void kernel_launch(void* const* d_in, const int* in_sizes, int n_in,
                              void* d_out, int out_size, void* d_ws, size_t ws_size,
                              hipStream_t stream) {
  const float* stu_x     = (const float*)d_in[0];
  const float* item_x    = (const float*)d_in[1];
  const float* conc_x    = (const float*)d_in[2];
  const float* stu_raw_x = (const float*)d_in[3];
  const float* W_cc  = (const float*)d_in[4];
  const float* al_cc = (const float*)d_in[5];
  const float* ar_cc = (const float*)d_in[6];
  const float* W_ic  = (const float*)d_in[7];
  const float* al_ic = (const float*)d_in[8];
  const float* ar_ic = (const float*)d_in[9];
  const float* al_cce = (const float*)d_in[10];
  const float* ar_cce = (const float*)d_in[11];
  const float* al_ice = (const float*)d_in[12];
  const float* ar_ice = (const float*)d_in[13];
  const float* W_ci  = (const float*)d_in[14];
  const float* al_ci = (const float*)d_in[15];
  const float* ar_ci = (const float*)d_in[16];
  const float* W_si  = (const float*)d_in[17];
  const float* al_si = (const float*)d_in[18];
  const float* ar_si = (const float*)d_in[19];
  const float* W_is  = (const float*)d_in[22];
  const float* al_is = (const float*)d_in[23];
  const float* ar_is = (const float*)d_in[24];
  const int* cc_src  = (const int*)d_in[25];
  const int* cc_dst  = (const int*)d_in[26];
  const int* ic_item = (const int*)d_in[27];
  const int* ic_conc = (const int*)d_in[28];
  const int* si_stu  = (const int*)d_in[29];
  const int* si_item = (const int*)d_in[30];

  char* wsb = (char*)d_ws;
  size_t off = 0;
  auto alloc = [&](size_t bytes) -> void* {
    void* p = wsb + off;
    off = (off + bytes + 255) & ~(size_t)255;
    return p;
  };

  s8* concWcc = (s8*)alloc((size_t)CONC_N * 128);
  s8* itemWic = (s8*)alloc((size_t)ITEM_N * 128);
  s8* concWci = (s8*)alloc((size_t)CONC_N * 128);
  s8* stuWsi  = (s8*)alloc((size_t)STU_N  * 128);
  s8* itemWis = (s8*)alloc((size_t)ITEM_N * 128);
  float2* ssc_cc = (float2*)alloc((size_t)CONC_N * 8);
  float2* ssc_ic = (float2*)alloc((size_t)ITEM_N * 8);
  float2* ssc_ci = (float2*)alloc((size_t)CONC_N * 8);
  float2* ssc_si = (float2*)alloc((size_t)STU_N * 8);
  float2* ssc_is = (float2*)alloc((size_t)ITEM_N * 8);
  ushort* Wbf[5];
  for (int i = 0; i < 5; ++i) Wbf[i] = (ushort*)alloc(128 * 128 * 2);
  float* c1buf   = (float*)alloc((size_t)CONC_N * 128 * 4);
  float* c2buf   = (float*)alloc((size_t)CONC_N * 128 * 4);
  float* vecs    = (float*)alloc(10 * 128 * 4);
  float* sr_cc  = (float*)alloc(CONC_N * 4);
  float* sr_ic  = (float*)alloc(CONC_N * 4);
  float* sr_ci  = (float*)alloc(ITEM_N * 4);
  float* sr_si  = (float*)alloc(ITEM_N * 4);
  float* sr_is  = (float*)alloc(STU_N * 4);
  float* sl_cce = (float*)alloc(CONC_N * 4);
  float* sr_cce = (float*)alloc(CONC_N * 4);
  float* sl_ice = (float*)alloc(CONC_N * 4);
  float* sr_ice = (float*)alloc(CONC_N * 4);

  unsigned* keys0 = (unsigned*)alloc((size_t)NE_CC * 4);
  unsigned* keys1 = (unsigned*)alloc((size_t)NE_IC * 4);
  unsigned* keys2 = (unsigned*)alloc((size_t)NE_IC * 4);
  unsigned* keys3 = (unsigned*)alloc((size_t)NE_SI * 4);
  unsigned* keys4 = (unsigned*)alloc((size_t)NE_SI * 4);
  int* srcs0 = (int*)alloc((size_t)NE_CC * 4);
  int* srcs1 = (int*)alloc((size_t)NE_IC * 4);
  int* srcs2 = (int*)alloc((size_t)NE_IC * 4);
  int* srcs3 = (int*)alloc((size_t)NE_SI * 4);
  int* srcs4 = (int*)alloc((size_t)NE_SI * 4);
  int* offs0 = (int*)alloc((CONC_N + 1) * 4);
  int* offs1 = (int*)alloc((CONC_N + 1) * 4);
  int* offs2 = (int*)alloc((ITEM_N + 1) * 4);
  int* offs3 = (int*)alloc((ITEM_N + 1) * 4);
  int* offs4 = (int*)alloc((STU_N + 1) * 4);
  int* pcnt      = (int*)alloc(5 * 32 * 128 * 4);
  int* cur_all   = (int*)alloc(TBUCK * 4);
  int* bases_all = (int*)alloc((TBUCK + 5) * 4);

  float* out = (float*)d_out;
  float* out_conc = out;
  float* out_item = out + (size_t)CONC_N * 128;
  float* out_stu  = out + (size_t)(CONC_N + ITEM_N) * 128;

  MegaArgs A;
  A.p[0] = {W_cc, al_cc, vecs + 0 * 128};
  A.p[1] = {W_cc, ar_cc, vecs + 1 * 128};
  A.p[2] = {W_ic, al_ic, vecs + 2 * 128};
  A.p[3] = {W_ic, ar_ic, vecs + 3 * 128};
  A.p[4] = {W_ci, al_ci, vecs + 4 * 128};
  A.p[5] = {W_ci, ar_ci, vecs + 5 * 128};
  A.p[6] = {W_si, al_si, vecs + 6 * 128};
  A.p[7] = {W_si, ar_si, vecs + 7 * 128};
  A.p[8] = {W_is, al_is, vecs + 8 * 128};
  A.p[9] = {W_is, ar_is, vecs + 9 * 128};
  A.G.g[0] = {cc_dst,  cc_src,  keys0, srcs0, offs0, NE_CC, CONC_N, 5, 63,   0,   0};
  A.G.g[1] = {ic_conc, ic_item, keys1, srcs1, offs1, NE_IC, CONC_N, 5, 63,  63,  64};
  A.G.g[2] = {ic_item, ic_conc, keys2, srcs2, offs2, NE_IC, ITEM_N, 8, 79, 126, 128};
  A.G.g[3] = {si_item, si_stu,  keys3, srcs3, offs3, NE_SI, ITEM_N, 8, 79, 205, 208};
  A.G.g[4] = {si_stu,  si_item, keys4, srcs4, offs4, NE_SI, STU_N,  9, 98, 284, 288};
  A.pcnt = pcnt;
  A.wsrc[0] = W_cc; A.wsrc[1] = W_ic; A.wsrc[2] = W_ci;
  A.wsrc[3] = W_si; A.wsrc[4] = W_is;
  for (int i = 0; i < 5; ++i) A.wdst[i] = Wbf[i];
  A.cur = cur_all; A.bases = bases_all;
  A.C.g[0] = {conc_x, concWcc, ssc_cc, CONC_N, 0,
              {vecs + 0 * 128, vecs + 1 * 128, vecs + 3 * 128, vecs + 4 * 128, ar_cce, ar_ice},
              {(float*)ssc_cc, sr_cc, sr_ic, (float*)ssc_ci, sr_cce, sr_ice},
              {2, 1, 1, 2, 1, 1}};
  A.C.g[1] = {item_x, itemWic, ssc_ic, ITEM_N, 32,
              {vecs + 2 * 128, vecs + 5 * 128, vecs + 7 * 128, vecs + 8 * 128, nullptr, nullptr},
              {(float*)ssc_ic, sr_ci, sr_si, (float*)ssc_is, nullptr, nullptr},
              {2, 1, 1, 2, 1, 1}};
  A.C.g[2] = {conc_x, concWci, ssc_ci, CONC_N, 345,
              {nullptr, nullptr, nullptr, nullptr, nullptr, nullptr},
              {nullptr, nullptr, nullptr, nullptr, nullptr, nullptr},
              {1, 1, 1, 1, 1, 1}};
  A.C.g[3] = {stu_x, stuWsi, ssc_si, STU_N, 377,
              {vecs + 6 * 128, nullptr, nullptr, nullptr, nullptr, nullptr},
              {(float*)ssc_si, nullptr, nullptr, nullptr, nullptr, nullptr},
              {2, 1, 1, 1, 1, 1}};
  A.C.g[4] = {item_x, itemWis, ssc_is, ITEM_N, 1159,
              {nullptr, nullptr, nullptr, nullptr, nullptr, nullptr},
              {nullptr, nullptr, nullptr, nullptr, nullptr, nullptr},
              {1, 1, 1, 1, 1, 1}};
  A.rx = stu_raw_x; A.rv = vecs + 9 * 128; A.ro = sr_is;
  A.GA.offs4 = offs4; A.GA.srcs4 = srcs4; A.GA.ssc_is = ssc_is; A.GA.sr_is = sr_is;
  A.GA.x_is = itemWis; A.GA.stu_raw_x = stu_raw_x; A.GA.out_stu = out_stu;
  A.GA.offs3 = offs3; A.GA.srcs3 = srcs3; A.GA.ssc_si = ssc_si; A.GA.sr_si = sr_si;
  A.GA.x_si = stuWsi;
  A.GA.offs2 = offs2; A.GA.srcs2 = srcs2; A.GA.ssc_ci = ssc_ci; A.GA.sr_ci = sr_ci;
  A.GA.x_ci = concWci; A.GA.item_x = item_x; A.GA.out_item = out_item;
  A.GA.offs0 = offs0; A.GA.srcs0 = srcs0; A.GA.ssc_cc = ssc_cc; A.GA.sr_cc = sr_cc;
  A.GA.x_cc = concWcc; A.GA.al_cce = al_cce; A.GA.c1 = c1buf; A.GA.sl_cce = sl_cce;
  A.GA.offs1 = offs1; A.GA.srcs1 = srcs1; A.GA.ssc_ic = ssc_ic; A.GA.sr_ic = sr_ic;
  A.GA.x_ic = itemWic; A.GA.al_ice = al_ice; A.GA.c2 = c2buf; A.GA.sl_ice = sl_ice;
  A.sr_cce = sr_cce; A.sr_ice = sr_ice;
  A.conc_x = conc_x; A.out_conc = out_conc;

  // cooperative mega-kernel; fall back to 6 serial launches on failure
  int maxb = 0;
  hipError_t oe = hipOccupancyMaxActiveBlocksPerMultiprocessor(&maxb, mega_k, 256, 0);
  if (oe != hipSuccess || maxb < 1) maxb = 4;
  int grid = maxb * 256;              // 256 CUs on MI355X
  if (grid > NB_D) grid = NB_D;
  void* kargs[] = { (void*)&A };
  hipError_t le = hipLaunchCooperativeKernel((void*)mega_k, dim3(grid), dim3(256),
                                             kargs, 0, stream);
  if (le != hipSuccess) {
    f_A<<<175, 256, 0, stream>>>(A);
    f_scan<<<1, 256, 0, stream>>>(A);
    f_B<<<NB_B, 256, 0, stream>>>(A);
    f_C<<<TBUCK, 256, 0, stream>>>(A);
    f_D<<<NB_D, 256, 0, stream>>>(A);
    f_E<<<NB_E, 256, 0, stream>>>(A);
  }
}

// Round 19
// 174.788 us; speedup vs baseline: 3.4128x; 3.4128x over previous
//
#include <hip/hip_runtime.h>

#define CONC_N 2000
#define ITEM_N 20000
#define STU_N  50000
#define NE_CC  40000
#define NE_IC  80000
#define NE_SI  1000000
#define TBUCK  382   // 63+63+79+79+98

typedef unsigned int uint;
typedef unsigned short ushort;
typedef signed char s8;
typedef __attribute__((ext_vector_type(8))) short bf16x8;
typedef __attribute__((ext_vector_type(4))) float f32x4;

__device__ __forceinline__ ushort f2bf(float f) {
  uint u = __float_as_uint(f);
  uint r = (u + 0x7FFFu + ((u >> 16) & 1u)) >> 16;
  return (ushort)r;
}

__device__ __forceinline__ bf16x8 packfrag(float4 lo, float4 hi) {
  union { bf16x8 s; uint u[4]; } p;
  p.u[0] = (uint)f2bf(lo.x) | ((uint)f2bf(lo.y) << 16);
  p.u[1] = (uint)f2bf(lo.z) | ((uint)f2bf(lo.w) << 16);
  p.u[2] = (uint)f2bf(hi.x) | ((uint)f2bf(hi.y) << 16);
  p.u[3] = (uint)f2bf(hi.z) | ((uint)f2bf(hi.w) << 16);
  return p.s;
}

// ---------------- CSR structures ----------------

struct CsrG {
  const int* dst; const int* src;
  unsigned* keys; int* srcs; int* offs;
  int E, n, shift, nbuck, tb, sb;
};
struct CsrGs { CsrG g[5]; };

// ------- setup: proj vectors (LDS-staged) + CSR histograms + W->frag-bf16 --

struct ProjDesc { const float* W; const float* a; float* out; };
struct SetupArgs {
  ProjDesc p[10];
  CsrGs G;
  int* pcnt;                 // [5*32][128]
  const float* wsrc[5];
  ushort* wdst[5];           // fragment-ordered bf16, 2048 recs x 16B
};

__global__ __launch_bounds__(256) void setup_k(SetupArgs A) {
  int b = blockIdx.x;
  int tid = threadIdx.x;
  if (b < 10) {              // proj: out = W^T a, LDS-staged coalesced
    __shared__ float Wl[128 * 132];
    __shared__ float a_s[128];
    ProjDesc d = A.p[b];
    #pragma unroll
    for (int i = 0; i < 16; ++i) {
      int s = tid + i * 256;
      int row = s >> 5, c4 = s & 31;
      float4 w = *(const float4*)&d.W[s * 4];
      float* dst = &Wl[row * 132 + c4 * 4];
      dst[0] = w.x; dst[1] = w.y; dst[2] = w.z; dst[3] = w.w;
    }
    if (tid < 128) a_s[tid] = d.a[tid];
    __syncthreads();
    if (tid < 128) {
      float acc = 0.f;
      #pragma unroll 4
      for (int j = 0; j < 128; ++j) acc += Wl[j * 132 + tid] * a_s[j];
      d.out[tid] = acc;
    }
    return;
  }
  if (b >= 170) {            // W fp32 -> fragment-ordered bf16
    int wi = b - 170;
    const float* Ws = A.wsrc[wi];
    ushort* Wd = A.wdst[wi];
    for (int rec = tid; rec < 2048; rec += 256) {
      int lane = rec & 63;
      int kk = (rec >> 6) & 3;
      int nt = rec >> 8;
      int x = lane & 15, g = lane >> 4;
      const float* src = &Ws[(nt * 16 + x) * 128 + kk * 32 + 4 * g];
      float4 lo = *(const float4*)src;
      float4 hi = *(const float4*)(src + 16);
      bf16x8 pk = packfrag(lo, hi);
      *(bf16x8*)&Wd[rec * 8] = pk;
    }
    return;
  }
  int bsel = b - 10;            // 0..159: histogram
  int gi = bsel >> 5, blk = bsel & 31;
  CsrG g = A.G.g[gi];
  __shared__ int lcnt[128];
  if (tid < 128) lcnt[tid] = 0;
  __syncthreads();
  int chunk = (g.E + 31) >> 5;
  int e0 = blk * chunk, e1 = min(g.E, e0 + chunk);
  for (int e = e0 + tid; e < e1; e += 256)
    atomicAdd(&lcnt[g.dst[e] >> g.shift], 1);
  __syncthreads();
  if (tid < 128) A.pcnt[bsel * 128 + tid] = lcnt[tid];
}

// ---------------- CSR scan ----------------

__global__ __launch_bounds__(512) void csr_scan(CsrGs G, const int* __restrict__ pcnt,
                                                int* __restrict__ cur, int* __restrict__ bases) {
  __shared__ int lc[TBUCK];
  __shared__ int lb[TBUCK + 5];
  int tid = threadIdx.x, lane = tid & 63, wv = tid >> 6;
  if (tid < TBUCK) {
    int gi = 0;
    #pragma unroll
    for (int k = 1; k < 5; ++k) if (tid >= G.g[k].tb) gi = k;
    int b = tid - G.g[gi].tb;
    int s = 0;
    for (int blk = 0; blk < 32; ++blk) s += pcnt[((gi << 5) + blk) * 128 + b];
    lc[tid] = s;
  }
  __syncthreads();
  if (wv < 5) {
    CsrG g = G.g[wv];
    int carry = 0;
    for (int base = 0; base < g.nbuck; base += 64) {
      int idx = base + lane;
      int v = (idx < g.nbuck) ? lc[g.tb + idx] : 0;
      int incl = v;
      #pragma unroll
      for (int o = 1; o < 64; o <<= 1) {
        int y = __shfl_up(incl, o);
        if (lane >= o) incl += y;
      }
      if (idx < g.nbuck) lb[g.sb + idx] = carry + incl - v;
      carry += __shfl(incl, 63);
    }
    if (lane == 0) lb[g.sb + g.nbuck] = carry;
  }
  __syncthreads();
  if (tid < TBUCK + 5) bases[tid] = lb[tid];
  if (tid < TBUCK) {
    int gi = 0;
    for (int k = 1; k < 5; ++k) if (tid >= G.g[k].tb) gi = k;
    cur[tid] = lb[tid + gi];
  }
  if (tid < 5) G.g[tid].offs[G.g[tid].n] = G.g[tid].E;
}

// ------------- mid3_k: csr_partition (600 blks) ∥ rdot (1024 blks) --------

__device__ void partition_body(const CsrGs& G, int* __restrict__ cur, int gi, int bx,
                               int nbx, unsigned char* smem) {
  CsrG g = G.g[gi];
  unsigned* ck = (unsigned*)smem;                 // 16384 B
  unsigned char* cb = smem + 16384;               // 4096 B
  int* lcnt = (int*)(smem + 20480);               // 512 B
  int* lcur = (int*)(smem + 20992);               // 512 B
  int tid = threadIdx.x;
  unsigned dmask = (1u << g.shift) - 1;
  for (int c0 = bx * 4096; c0 < g.E; c0 += nbx * 4096) {
    if (tid < 128) lcnt[tid] = 0;
    __syncthreads();
    #pragma unroll
    for (int i = 0; i < 16; ++i) {
      int e = c0 + i * 256 + tid;
      if (e < g.E) {
        int d = g.dst[e], s = g.src[e];
        int b = d >> g.shift;
        ck[i * 256 + tid] = ((unsigned)(d & dmask) << 16) | (unsigned)s;
        cb[i * 256 + tid] = (unsigned char)b;
        atomicAdd(&lcnt[b], 1);
      } else cb[i * 256 + tid] = 255;
    }
    __syncthreads();
    if (tid < g.nbuck && lcnt[tid] > 0) lcur[tid] = atomicAdd(&cur[g.tb + tid], lcnt[tid]);
    __syncthreads();
    #pragma unroll
    for (int i = 0; i < 16; ++i) {
      int b = cb[i * 256 + tid];
      if (b != 255) {
        int pos = atomicAdd(&lcur[b], 1);
        g.keys[pos] = ck[i * 256 + tid];
      }
    }
    __syncthreads();
  }
}

__device__ void rdot_body(const float* __restrict__ x, const float* __restrict__ v,
                          float* __restrict__ o, int n, int blk, int nblk) {
  int lane = threadIdx.x & 63;
  int wid = (blk * 256 + threadIdx.x) >> 6;
  int nw = nblk * 4;
  float va = v[lane], vb = v[64 + lane];
  for (int r = wid; r < n; r += nw) {
    float a = x[r * 128 + lane] * va + x[r * 128 + 64 + lane] * vb;
    #pragma unroll
    for (int of = 32; of; of >>= 1) a += __shfl_xor(a, of);
    if (lane == 0) o[r] = a;
  }
}

__global__ __launch_bounds__(256) void mid3_k(CsrGs G, int* cur,
                                              const float* rx, const float* rv,
                                              float* ro, int rnb) {
  __shared__ __align__(16) unsigned char smem[21504];
  int b = blockIdx.x;
  if (b < 600) {
    partition_body(G, cur, b / 120, b % 120, 120, smem);
  } else {
    rdot_body(rx, rv, ro, STU_N, b - 600, rnb);
  }
}

// ------------- mid4_k: build_lite (382 blks) ∥ MFMA GEMMs -----------------
// GEMM emits s8 codes + packed (score,scale) float2 tables.

struct GemmDesc { const float* X; s8* Y8; float2* SS; int n, b0;
                  const float* dv[6]; float* dq[6]; int ds[6]; };
struct BigC {
  GemmDesc g[5];
  int gemm_blocks;
};

__device__ void build_lite(const CsrGs& G, const int* __restrict__ bases, int bid,
                           int* lh, int* lex, int* lcu, int* wsum) {
  int gi = 0;
  for (int k = 1; k < 5; ++k) if (bid >= G.g[k].tb) gi = k;
  CsrG g = G.g[gi];
  int b = bid - g.tb;
  int base = bases[g.sb + b];
  int cnt = bases[g.sb + b + 1] - base;

  int tid = threadIdx.x;
  lh[tid] = 0; lh[tid + 256] = 0;
  __syncthreads();
  for (int j = tid; j < cnt; j += 256)
    atomicAdd(&lh[g.keys[base + j] >> 16], 1);
  __syncthreads();
  int a0 = lh[2 * tid], a1 = lh[2 * tid + 1];
  int pair = a0 + a1;
  int lane = tid & 63, wv = tid >> 6;
  int incl = pair;
  #pragma unroll
  for (int o = 1; o < 64; o <<= 1) {
    int y = __shfl_up(incl, o);
    if (lane >= o) incl += y;
  }
  if (lane == 63) wsum[wv] = incl;
  __syncthreads();
  if (tid == 0) {
    int s = 0;
    #pragma unroll
    for (int w = 0; w < 4; ++w) { int t = wsum[w]; wsum[w] = s; s += t; }
  }
  __syncthreads();
  int ep = wsum[wv] + incl - pair;
  lex[2 * tid] = ep;       lex[2 * tid + 1] = ep + a0;
  lcu[2 * tid] = ep;       lcu[2 * tid + 1] = ep + a0;
  __syncthreads();
  int dst0 = b << g.shift;
  int ndst = min(1 << g.shift, g.n - dst0);
  for (int dl = tid; dl < ndst; dl += 256) g.offs[dst0 + dl] = base + lex[dl];
  for (int j = tid; j < cnt; j += 256) {
    unsigned k = g.keys[base + j];
    int dl = k >> 16;
    int pos = atomicAdd(&lcu[dl], 1);
    g.srcs[base + pos] = (int)(k & 0xFFFFu);
  }
}

template <int NV>
__device__ void gemm_bodyT(const GemmDesc& gd, const ushort* __restrict__ Wf, int blk) {
  int tid = threadIdx.x;
  int lane = tid & 63, wv = tid >> 6;
  int x = lane & 15, g = lane >> 4;
  int row = blk * 64 + wv * 16 + x;
  const float* xr = &gd.X[(size_t)(row < gd.n ? row : 0) * 128];
  bf16x8 afrag[4];
  float dacc[NV == 0 ? 1 : NV];
  #pragma unroll
  for (int v = 0; v < NV; ++v) dacc[v] = 0.f;
  #pragma unroll
  for (int kk = 0; kk < 4; ++kk) {
    float4 lo = *(const float4*)&xr[kk * 32 + 4 * g];
    float4 hi = *(const float4*)&xr[kk * 32 + 16 + 4 * g];
    afrag[kk] = packfrag(lo, hi);
    #pragma unroll
    for (int v = 0; v < NV; ++v) {
      const float* vp = gd.dv[v];
      float4 vlo = *(const float4*)&vp[kk * 32 + 4 * g];
      float4 vhi = *(const float4*)&vp[kk * 32 + 16 + 4 * g];
      dacc[v] += lo.x * vlo.x + lo.y * vlo.y + lo.z * vlo.z + lo.w * vlo.w
               + hi.x * vhi.x + hi.y * vhi.y + hi.z * vhi.z + hi.w * vhi.w;
    }
  }
  #pragma unroll
  for (int v = 0; v < NV; ++v) {
    float dsum = dacc[v];
    dsum += __shfl_xor(dsum, 16);
    dsum += __shfl_xor(dsum, 32);
    if (lane < 16 && row < gd.n) gd.dq[v][(size_t)row * gd.ds[v]] = dsum;
  }
  f32x4 acc[8];
  #pragma unroll
  for (int t = 0; t < 8; ++t) acc[t] = (f32x4){0.f, 0.f, 0.f, 0.f};
  #pragma unroll
  for (int nt = 0; nt < 8; ++nt) {
    #pragma unroll
    for (int kk = 0; kk < 4; ++kk) {
      union { uint4 u; bf16x8 s; } bu;
      bu.u = *(const uint4*)&Wf[(size_t)((nt * 4 + kk) * 64 + lane) * 8];
      acc[nt] = __builtin_amdgcn_mfma_f32_16x16x32_bf16(afrag[kk], bu.s, acc[nt], 0, 0, 0);
    }
  }
  // D layout: col = lane&15, row = (lane>>4)*4 + r. Quantize per row to s8.
  int orow = blk * 64 + wv * 16 + 4 * g;
  #pragma unroll
  for (int r = 0; r < 4; ++r) {
    float m8 = 0.f;
    #pragma unroll
    for (int nt = 0; nt < 8; ++nt) m8 = fmaxf(m8, fabsf(acc[nt][r]));
    #pragma unroll
    for (int msk = 1; msk < 16; msk <<= 1) m8 = fmaxf(m8, __shfl_xor(m8, msk));
    int gr = orow + r;
    if (gr < gd.n) {
      float invs = (m8 > 0.f) ? 127.f / m8 : 0.f;
      if (x == 0) gd.SS[gr].y = m8 * (1.f / 127.f);
      #pragma unroll
      for (int nt = 0; nt < 8; ++nt) {
        int q = (int)rintf(acc[nt][r] * invs);
        gd.Y8[(size_t)gr * 128 + nt * 16 + x] = (s8)q;
      }
    }
  }
}

__global__ __launch_bounds__(256, 2) void mid4_k(CsrGs G, const int* bases, BigC C,
                                                 const ushort* W0, const ushort* W1,
                                                 const ushort* W2, const ushort* W3,
                                                 const ushort* W4) {
  __shared__ int lh[512], lex[512], lcu[512], wsum[4];
  int b = blockIdx.x;
  if (b < TBUCK) {
    build_lite(G, bases, b, lh, lex, lcu, wsum);
    return;
  }
  b -= TBUCK;
  if (b < C.g[1].b0)      gemm_bodyT<6>(C.g[0], W0, b - C.g[0].b0);
  else if (b < C.g[2].b0) gemm_bodyT<4>(C.g[1], W1, b - C.g[1].b0);
  else if (b < C.g[3].b0) gemm_bodyT<0>(C.g[2], W2, b - C.g[2].b0);
  else if (b < C.g[4].b0) gemm_bodyT<1>(C.g[3], W3, b - C.g[3].b0);
  else                    gemm_bodyT<0>(C.g[4], W4, b - C.g[4].b0);
}

// ---------------- GAT core: no-max softmax, packed (score,scale) gather ---

__device__ __forceinline__ void fma8q(float acc[8], float wj, uint2 u) {
  int lo = (int)u.x, hi = (int)u.y;
  acc[0] += wj * (float)((lo << 24) >> 24);
  acc[1] += wj * (float)((lo << 16) >> 24);
  acc[2] += wj * (float)((lo << 8) >> 24);
  acc[3] += wj * (float)(lo >> 24);
  acc[4] += wj * (float)((hi << 24) >> 24);
  acc[5] += wj * (float)((hi << 16) >> 24);
  acc[6] += wj * (float)((hi << 8) >> 24);
  acc[7] += wj * (float)(hi >> 24);
}

// t = t4 + (lane>>4); lane il = lane&15 owns dims il*8..il*8+7 (s8 codes).
// Direct exp (scores ~N(0,2); fminf(...,80) overflow guard), 4-deep loads.
__device__ void gat_core16(const int* __restrict__ offs, const int* __restrict__ srcs,
                           const float2* __restrict__ ssc, const float* __restrict__ sr,
                           const s8* __restrict__ x8,
                           int t4, int n_tgt, int lane, float acc[8]) {
  int q = lane >> 4, il = lane & 15;
  int t = t4 + q;
  bool tv = t < n_tgt;
  int sbeg = tv ? offs[t] : 0;
  int send = tv ? offs[t + 1] : 0;
  float srt = tv ? sr[t] : 0.f;

  float se = 0.f;
  #pragma unroll
  for (int r = 0; r < 8; ++r) acc[r] = 0.f;
  int qb = q << 4;

  for (int i0 = sbeg; i0 < send; i0 += 16) {
    int cnt = min(16, send - i0);
    int s = 0; float w = 0.f, ws = 0.f;
    if (il < cnt) {
      s = srcs[i0 + il];
      float2 ss = ssc[s];
      float ee = ss.x + srt;
      ee = ee > 0.f ? ee : 0.2f * ee;
      w = __expf(fminf(ee, 80.f));
      ws = w * ss.y;
    }
    se += w;
    int j = 0;
    for (; j + 4 <= cnt; j += 4) {
      int sj0 = __shfl(s, qb + j);
      int sj1 = __shfl(s, qb + j + 1);
      int sj2 = __shfl(s, qb + j + 2);
      int sj3 = __shfl(s, qb + j + 3);
      float wj0 = __shfl(ws, qb + j);
      float wj1 = __shfl(ws, qb + j + 1);
      float wj2 = __shfl(ws, qb + j + 2);
      float wj3 = __shfl(ws, qb + j + 3);
      uint2 u0 = *(const uint2*)&x8[(size_t)sj0 * 128 + il * 8];
      uint2 u1 = *(const uint2*)&x8[(size_t)sj1 * 128 + il * 8];
      uint2 u2 = *(const uint2*)&x8[(size_t)sj2 * 128 + il * 8];
      uint2 u3 = *(const uint2*)&x8[(size_t)sj3 * 128 + il * 8];
      fma8q(acc, wj0, u0);
      fma8q(acc, wj1, u1);
      fma8q(acc, wj2, u2);
      fma8q(acc, wj3, u3);
    }
    for (; j < cnt; ++j) {
      int sj = __shfl(s, qb + j);
      float wj = __shfl(ws, qb + j);
      uint2 u = *(const uint2*)&x8[(size_t)sj * 128 + il * 8];
      fma8q(acc, wj, u);
    }
  }
  // reduce se across the 16-lane group, normalize
  #pragma unroll
  for (int o = 8; o; o >>= 1) se += __shfl_xor(se, o);
  float inv = 1.f / (se + 1e-16f);
  #pragma unroll
  for (int r = 0; r < 8; ++r) acc[r] *= inv;
}

__device__ __forceinline__ void gat_store16(const float acc[8], const float* base0,
                                            float* out, int t4, int n_tgt, int lane) {
  int q = lane >> 4, il = lane & 15;
  int t = t4 + q;
  if (t >= n_tgt) return;
  int d = t * 128 + il * 8;
  float4 a0 = make_float4(acc[0], acc[1], acc[2], acc[3]);
  float4 a1 = make_float4(acc[4], acc[5], acc[6], acc[7]);
  if (base0) {
    const float4 b0 = *(const float4*)&base0[d];
    const float4 b1 = *(const float4*)&base0[d + 4];
    a0.x += b0.x; a0.y += b0.y; a0.z += b0.z; a0.w += b0.w;
    a1.x += b1.x; a1.y += b1.y; a1.z += b1.z; a1.w += b1.w;
  }
  *(float4*)&out[d] = a0;
  *(float4*)&out[d + 4] = a1;
}

__device__ void c1c2_body16(const int* offs, const int* srcs, const float2* ssc,
                            const float* sr, const s8* x8,
                            const float* al, float* o, float* slo,
                            int t4, int n_tgt, int lane) {
  float acc[8];
  gat_core16(offs, srcs, ssc, sr, x8, t4, n_tgt, lane, acc);
  int q = lane >> 4, il = lane & 15;
  int t = t4 + q;
  float4 v0 = *(const float4*)&al[il * 8];
  float4 v1 = *(const float4*)&al[il * 8 + 4];
  float p = acc[0] * v0.x + acc[1] * v0.y + acc[2] * v0.z + acc[3] * v0.w +
            acc[4] * v1.x + acc[5] * v1.y + acc[6] * v1.z + acc[7] * v1.w;
  #pragma unroll
  for (int o2 = 8; o2; o2 >>= 1) p += __shfl_xor(p, o2);
  if (t < n_tgt) {
    if (il == 0) slo[t] = p;
    int d = t * 128 + il * 8;
    *(float4*)&o[d] = make_float4(acc[0], acc[1], acc[2], acc[3]);
    *(float4*)&o[d + 4] = make_float4(acc[4], acc[5], acc[6], acc[7]);
  }
}

// dual (fp32 gather of c1/c2 on cc graph), wave per target (small)
__device__ void gat_dual_core(const int* __restrict__ offs, const int* __restrict__ srcs,
                              const float* __restrict__ sl1, const float* __restrict__ sr1,
                              const float* __restrict__ xl1,
                              const float* __restrict__ sl2, const float* __restrict__ sr2,
                              const float* __restrict__ xl2,
                              const float* __restrict__ base,
                              float* __restrict__ out, int t, int lane) {
  int sbeg = offs[t], send = offs[t + 1];
  float srt1 = sr1[t], srt2 = sr2[t];
  float m1 = -1e30f, m2 = -1e30f;
  for (int i = sbeg + lane; i < send; i += 64) {
    int s = srcs[i];
    float e1 = sl1[s] + srt1; e1 = e1 > 0.f ? e1 : 0.2f * e1;
    float e2 = sl2[s] + srt2; e2 = e2 > 0.f ? e2 : 0.2f * e2;
    m1 = fmaxf(m1, e1); m2 = fmaxf(m2, e2);
  }
  #pragma unroll
  for (int o = 32; o; o >>= 1) {
    m1 = fmaxf(m1, __shfl_xor(m1, o));
    m2 = fmaxf(m2, __shfl_xor(m2, o));
  }
  float se1 = 0.f, se2 = 0.f;
  for (int i = sbeg + lane; i < send; i += 64) {
    int s = srcs[i];
    float e1 = sl1[s] + srt1; e1 = e1 > 0.f ? e1 : 0.2f * e1;
    float e2 = sl2[s] + srt2; e2 = e2 > 0.f ? e2 : 0.2f * e2;
    se1 += __expf(e1 - m1); se2 += __expf(e2 - m2);
  }
  #pragma unroll
  for (int o = 32; o; o >>= 1) {
    se1 += __shfl_xor(se1, o);
    se2 += __shfl_xor(se2, o);
  }
  float inv1 = 1.f / (se1 + 1e-16f), inv2 = 1.f / (se2 + 1e-16f);
  float ax = 0.f, ay = 0.f;
  for (int i0 = sbeg; i0 < send; i0 += 64) {
    int cnt = min(64, send - i0);
    int s = 0; float w1 = 0.f, w2 = 0.f;
    if (lane < cnt) {
      s = srcs[i0 + lane];
      float e1 = sl1[s] + srt1; e1 = e1 > 0.f ? e1 : 0.2f * e1;
      float e2 = sl2[s] + srt2; e2 = e2 > 0.f ? e2 : 0.2f * e2;
      w1 = __expf(e1 - m1) * inv1;
      w2 = __expf(e2 - m2) * inv2;
    }
    for (int j = 0; j < cnt; ++j) {
      int sj = __shfl(s, j);
      float wj1 = __shfl(w1, j);
      float wj2 = __shfl(w2, j);
      const float2 v1 = *(const float2*)&xl1[sj * 128 + lane * 2];
      const float2 v2 = *(const float2*)&xl2[sj * 128 + lane * 2];
      ax += wj1 * v1.x + wj2 * v2.x;
      ay += wj1 * v1.y + wj2 * v2.y;
    }
  }
  const float2 b = *(const float2*)&base[t * 128 + lane * 2];
  float2 o2; o2.x = ax + b.x; o2.y = ay + b.y;
  *(float2*)&out[t * 128 + lane * 2] = o2;
}

// ---- gats_k: [i1+i2 merged | s1 | c1c2], heavy blocks first ---------------

#define NB_I12 1250   // ceil(20000/16)
#define NB_S1  3125   // ceil(50000/16)
#define NB_CC  125    // ceil(2000/16)

struct GatsArgs {
  const int *offs4, *srcs4; const float2* ssc_is; const float* sr_is;
  const s8* x_is; const float* stu_raw_x; float* out_stu;
  const int *offs3, *srcs3; const float2* ssc_si; const float* sr_si; const s8* x_si;
  const int *offs2, *srcs2; const float2* ssc_ci; const float* sr_ci; const s8* x_ci;
  const float* item_x; float* out_item;
  const int *offs0, *srcs0; const float2* ssc_cc; const float* sr_cc; const s8* x_cc;
  const float* al_cce; float *c1, *sl_cce;
  const int *offs1, *srcs1; const float2* ssc_ic; const float* sr_ic; const s8* x_ic;
  const float* al_ice; float *c2, *sl_ice;
};

__global__ void gats_k(GatsArgs A) {
  int b = blockIdx.x;
  int lane = threadIdx.x & 63;
  int wv = threadIdx.x >> 6;
  if (b < NB_I12) {
    int t4 = b * 16 + wv * 4;
    float acc1[8], acc2[8];
    gat_core16(A.offs2, A.srcs2, A.ssc_ci, A.sr_ci, A.x_ci, t4, ITEM_N, lane, acc1);
    gat_core16(A.offs3, A.srcs3, A.ssc_si, A.sr_si, A.x_si, t4, ITEM_N, lane, acc2);
    #pragma unroll
    for (int r = 0; r < 8; ++r) acc1[r] += acc2[r];
    gat_store16(acc1, A.item_x, A.out_item, t4, ITEM_N, lane);
  } else if (b < NB_I12 + NB_S1) {
    int t4 = (b - NB_I12) * 16 + wv * 4;
    float acc[8];
    gat_core16(A.offs4, A.srcs4, A.ssc_is, A.sr_is, A.x_is, t4, STU_N, lane, acc);
    gat_store16(acc, A.stu_raw_x, A.out_stu, t4, STU_N, lane);
  } else {
    int sub = b - NB_I12 - NB_S1;   // 0..2*NB_CC-1
    int which = sub >= NB_CC;
    int t4 = (sub - which * NB_CC) * 16 + wv * 4;
    if (!which)
      c1c2_body16(A.offs0, A.srcs0, A.ssc_cc, A.sr_cc, A.x_cc, A.al_cce,
                  A.c1, A.sl_cce, t4, CONC_N, lane);
    else
      c1c2_body16(A.offs1, A.srcs1, A.ssc_ic, A.sr_ic, A.x_ic, A.al_ice,
                  A.c2, A.sl_ice, t4, CONC_N, lane);
  }
}

// ---- fin_k: dual(conc) only ----------------------------------------------

__global__ void fin_k(const int* offs0, const int* srcs0,
                      const float* sl_cce, const float* sr_cce, const float* c1,
                      const float* sl_ice, const float* sr_ice, const float* c2,
                      const float* conc_x, float* out_conc) {
  int t = (blockIdx.x * blockDim.x + threadIdx.x) >> 6;
  if (t >= CONC_N) return;
  gat_dual_core(offs0, srcs0, sl_cce, sr_cce, c1, sl_ice, sr_ice, c2,
                conc_x, out_conc, t, threadIdx.x & 63);
}

// ---------------- launch ----------------

extern "C" void kernel_launch(void* const* d_in, const int* in_sizes, int n_in,
                              void* d_out, int out_size, void* d_ws, size_t ws_size,
                              hipStream_t stream) {
  const float* stu_x     = (const float*)d_in[0];
  const float* item_x    = (const float*)d_in[1];
  const float* conc_x    = (const float*)d_in[2];
  const float* stu_raw_x = (const float*)d_in[3];
  const float* W_cc  = (const float*)d_in[4];
  const float* al_cc = (const float*)d_in[5];
  const float* ar_cc = (const float*)d_in[6];
  const float* W_ic  = (const float*)d_in[7];
  const float* al_ic = (const float*)d_in[8];
  const float* ar_ic = (const float*)d_in[9];
  const float* al_cce = (const float*)d_in[10];
  const float* ar_cce = (const float*)d_in[11];
  const float* al_ice = (const float*)d_in[12];
  const float* ar_ice = (const float*)d_in[13];
  const float* W_ci  = (const float*)d_in[14];
  const float* al_ci = (const float*)d_in[15];
  const float* ar_ci = (const float*)d_in[16];
  const float* W_si  = (const float*)d_in[17];
  const float* al_si = (const float*)d_in[18];
  const float* ar_si = (const float*)d_in[19];
  const float* W_is  = (const float*)d_in[22];
  const float* al_is = (const float*)d_in[23];
  const float* ar_is = (const float*)d_in[24];
  const int* cc_src  = (const int*)d_in[25];
  const int* cc_dst  = (const int*)d_in[26];
  const int* ic_item = (const int*)d_in[27];
  const int* ic_conc = (const int*)d_in[28];
  const int* si_stu  = (const int*)d_in[29];
  const int* si_item = (const int*)d_in[30];

  char* wsb = (char*)d_ws;
  size_t off = 0;
  auto alloc = [&](size_t bytes) -> void* {
    void* p = wsb + off;
    off = (off + bytes + 255) & ~(size_t)255;
    return p;
  };

  // int8 W-product tables + packed (score,scale) float2 tables
  s8* concWcc = (s8*)alloc((size_t)CONC_N * 128);
  s8* itemWic = (s8*)alloc((size_t)ITEM_N * 128);
  s8* concWci = (s8*)alloc((size_t)CONC_N * 128);
  s8* stuWsi  = (s8*)alloc((size_t)STU_N  * 128);
  s8* itemWis = (s8*)alloc((size_t)ITEM_N * 128);
  float2* ssc_cc = (float2*)alloc((size_t)CONC_N * 8);
  float2* ssc_ic = (float2*)alloc((size_t)ITEM_N * 8);
  float2* ssc_ci = (float2*)alloc((size_t)CONC_N * 8);
  float2* ssc_si = (float2*)alloc((size_t)STU_N * 8);
  float2* ssc_is = (float2*)alloc((size_t)ITEM_N * 8);
  ushort* Wbf[5];
  for (int i = 0; i < 5; ++i) Wbf[i] = (ushort*)alloc(128 * 128 * 2);
  float* c1buf   = (float*)alloc((size_t)CONC_N * 128 * 4);
  float* c2buf   = (float*)alloc((size_t)CONC_N * 128 * 4);
  float* vecs    = (float*)alloc(10 * 128 * 4);
  float* sr_cc  = (float*)alloc(CONC_N * 4);
  float* sr_ic  = (float*)alloc(CONC_N * 4);
  float* sr_ci  = (float*)alloc(ITEM_N * 4);
  float* sr_si  = (float*)alloc(ITEM_N * 4);
  float* sr_is  = (float*)alloc(STU_N * 4);
  float* sl_cce = (float*)alloc(CONC_N * 4);
  float* sr_cce = (float*)alloc(CONC_N * 4);
  float* sl_ice = (float*)alloc(CONC_N * 4);
  float* sr_ice = (float*)alloc(CONC_N * 4);

  unsigned* keys0 = (unsigned*)alloc((size_t)NE_CC * 4);
  unsigned* keys1 = (unsigned*)alloc((size_t)NE_IC * 4);
  unsigned* keys2 = (unsigned*)alloc((size_t)NE_IC * 4);
  unsigned* keys3 = (unsigned*)alloc((size_t)NE_SI * 4);
  unsigned* keys4 = (unsigned*)alloc((size_t)NE_SI * 4);
  int* srcs0 = (int*)alloc((size_t)NE_CC * 4);
  int* srcs1 = (int*)alloc((size_t)NE_IC * 4);
  int* srcs2 = (int*)alloc((size_t)NE_IC * 4);
  int* srcs3 = (int*)alloc((size_t)NE_SI * 4);
  int* srcs4 = (int*)alloc((size_t)NE_SI * 4);
  int* offs0 = (int*)alloc((CONC_N + 1) * 4);
  int* offs1 = (int*)alloc((CONC_N + 1) * 4);
  int* offs2 = (int*)alloc((ITEM_N + 1) * 4);
  int* offs3 = (int*)alloc((ITEM_N + 1) * 4);
  int* offs4 = (int*)alloc((STU_N + 1) * 4);
  int* pcnt      = (int*)alloc(5 * 32 * 128 * 4);
  int* cur_all   = (int*)alloc(TBUCK * 4);
  int* bases_all = (int*)alloc((TBUCK + 5) * 4);

  float* out = (float*)d_out;
  float* out_conc = out;
  float* out_item = out + (size_t)CONC_N * 128;
  float* out_stu  = out + (size_t)(CONC_N + ITEM_N) * 128;

  CsrGs G;
  G.g[0] = {cc_dst,  cc_src,  keys0, srcs0, offs0, NE_CC, CONC_N, 5, 63,   0,   0};
  G.g[1] = {ic_conc, ic_item, keys1, srcs1, offs1, NE_IC, CONC_N, 5, 63,  63,  64};
  G.g[2] = {ic_item, ic_conc, keys2, srcs2, offs2, NE_IC, ITEM_N, 8, 79, 126, 128};
  G.g[3] = {si_item, si_stu,  keys3, srcs3, offs3, NE_SI, ITEM_N, 8, 79, 205, 208};
  G.g[4] = {si_stu,  si_item, keys4, srcs4, offs4, NE_SI, STU_N,  9, 98, 284, 288};

  // K1: setup (proj vectors + CSR histograms + W->frag-bf16)
  SetupArgs SA;
  SA.p[0] = {W_cc, al_cc, vecs + 0 * 128};
  SA.p[1] = {W_cc, ar_cc, vecs + 1 * 128};
  SA.p[2] = {W_ic, al_ic, vecs + 2 * 128};
  SA.p[3] = {W_ic, ar_ic, vecs + 3 * 128};
  SA.p[4] = {W_ci, al_ci, vecs + 4 * 128};
  SA.p[5] = {W_ci, ar_ci, vecs + 5 * 128};
  SA.p[6] = {W_si, al_si, vecs + 6 * 128};
  SA.p[7] = {W_si, ar_si, vecs + 7 * 128};
  SA.p[8] = {W_is, al_is, vecs + 8 * 128};
  SA.p[9] = {W_is, ar_is, vecs + 9 * 128};
  SA.G = G;
  SA.pcnt = pcnt;
  SA.wsrc[0] = W_cc; SA.wsrc[1] = W_ic; SA.wsrc[2] = W_ci;
  SA.wsrc[3] = W_si; SA.wsrc[4] = W_is;
  for (int i = 0; i < 5; ++i) SA.wdst[i] = Wbf[i];
  setup_k<<<175, 256, 0, stream>>>(SA);

  // K2: scan
  csr_scan<<<1, 512, 0, stream>>>(G, pcnt, cur_all, bases_all);

  // K3: partition (600) ∥ rdot (1024)
  mid3_k<<<600 + 1024, 256, 0, stream>>>(G, cur_all, stu_raw_x, vecs + 9 * 128,
                                         sr_is, 1024);

  // K4: build_lite (382) ∥ MFMA gemms (+fused dots -> packed ssc, s8 output)
  BigC C;
  C.g[0] = {conc_x, concWcc, ssc_cc, CONC_N, 0,
            {vecs + 0 * 128, vecs + 1 * 128, vecs + 3 * 128, vecs + 4 * 128, ar_cce, ar_ice},
            {(float*)ssc_cc, sr_cc, sr_ic, (float*)ssc_ci, sr_cce, sr_ice},
            {2, 1, 1, 2, 1, 1}};
  C.g[1] = {item_x, itemWic, ssc_ic, ITEM_N, 32,
            {vecs + 2 * 128, vecs + 5 * 128, vecs + 7 * 128, vecs + 8 * 128, nullptr, nullptr},
            {(float*)ssc_ic, sr_ci, sr_si, (float*)ssc_is, nullptr, nullptr},
            {2, 1, 1, 2, 1, 1}};
  C.g[2] = {conc_x, concWci, ssc_ci, CONC_N, 345,
            {nullptr, nullptr, nullptr, nullptr, nullptr, nullptr},
            {nullptr, nullptr, nullptr, nullptr, nullptr, nullptr},
            {1, 1, 1, 1, 1, 1}};
  C.g[3] = {stu_x, stuWsi, ssc_si, STU_N, 377,
            {vecs + 6 * 128, nullptr, nullptr, nullptr, nullptr, nullptr},
            {(float*)ssc_si, nullptr, nullptr, nullptr, nullptr, nullptr},
            {2, 1, 1, 1, 1, 1}};
  C.g[4] = {item_x, itemWis, ssc_is, ITEM_N, 1159,
            {nullptr, nullptr, nullptr, nullptr, nullptr, nullptr},
            {nullptr, nullptr, nullptr, nullptr, nullptr, nullptr},
            {1, 1, 1, 1, 1, 1}};
  C.gemm_blocks = 1472;
  mid4_k<<<TBUCK + 1472, 256, 0, stream>>>(G, bases_all, C,
                                           Wbf[0], Wbf[1], Wbf[2], Wbf[3], Wbf[4]);

  // K5: all independent GATs in one launch (i1+i2 | s1 | c1c2), heavy first
  GatsArgs GA;
  GA.offs4 = offs4; GA.srcs4 = srcs4; GA.ssc_is = ssc_is; GA.sr_is = sr_is;
  GA.x_is = itemWis; GA.stu_raw_x = stu_raw_x; GA.out_stu = out_stu;
  GA.offs3 = offs3; GA.srcs3 = srcs3; GA.ssc_si = ssc_si; GA.sr_si = sr_si;
  GA.x_si = stuWsi;
  GA.offs2 = offs2; GA.srcs2 = srcs2; GA.ssc_ci = ssc_ci; GA.sr_ci = sr_ci;
  GA.x_ci = concWci; GA.item_x = item_x; GA.out_item = out_item;
  GA.offs0 = offs0; GA.srcs0 = srcs0; GA.ssc_cc = ssc_cc; GA.sr_cc = sr_cc;
  GA.x_cc = concWcc; GA.al_cce = al_cce; GA.c1 = c1buf; GA.sl_cce = sl_cce;
  GA.offs1 = offs1; GA.srcs1 = srcs1; GA.ssc_ic = ssc_ic; GA.sr_ic = sr_ic;
  GA.x_ic = itemWic; GA.al_ice = al_ice; GA.c2 = c2buf; GA.sl_ice = sl_ice;
  gats_k<<<NB_I12 + NB_S1 + 2 * NB_CC, 256, 0, stream>>>(GA);

  // K6: dual (needs c1/c2 + their dots)
  fin_k<<<500, 256, 0, stream>>>(offs0, srcs0, sl_cce, sr_cce, c1buf,
                                 sl_ice, sr_ice, c2buf, conc_x, out_conc);
}